// Round 2
// baseline (311.578 us; speedup 1.0000x reference)
//
#include <hip/hip_runtime.h>
#include <hip/hip_bf16.h>

// GraphSAGE 3-layer forward, MI355X. Round 7:
//  - GEMM restructured: one block computes ALL output columns (Wl|Wr fused,
//    NJ=16 col-fragments layers 0/1, NJ=8 layer 2). A fragments loaded once,
//    reused NJ x from registers -> A fetch traffic /4 (R6's gemm<1> was
//    43.7us @ 50MB FETCH because each y-quadrant re-read the full f32 x).
//    16 rows/wave (acc[NJ] = 64 VGPR) keeps grid at 782x4 waves ~ 3/SIMD.
//  - x f32->bf16 cast stays fused into GEMM0 (now reads x exactly once).
//  - vectorized agg/final gathers (R6) kept; distribute/build (R5/R6) kept.

typedef __attribute__((ext_vector_type(8))) short bf16x8;
typedef __attribute__((ext_vector_type(4))) float f32x4;

#define NPB 128            // nodes per bucket (bucket = dst >> 7)
#define BCAP 2560          // per-bucket staging capacity (mean 2048, sd ~45)
#define EPB 8192           // edges per distribute block
#define EPT 32             // edges per thread (256 thr)
#define CPAD 16            // global counter stride in ints (64B line each)

__device__ __forceinline__ unsigned short f2bf(float f) {
    unsigned int u = __builtin_bit_cast(unsigned int, f);
    u += 0x7fffu + ((u >> 16) & 1u);           // round-to-nearest-even
    return (unsigned short)(u >> 16);
}
__device__ __forceinline__ float bf2f(unsigned int bits16) {
    return __builtin_bit_cast(float, bits16 << 16);
}
__device__ __forceinline__ bf16x8 pack8(float4 lo, float4 hi) {
    bf16x8 r;
    r[0] = (short)f2bf(lo.x); r[1] = (short)f2bf(lo.y);
    r[2] = (short)f2bf(lo.z); r[3] = (short)f2bf(lo.w);
    r[4] = (short)f2bf(hi.x); r[5] = (short)f2bf(hi.y);
    r[6] = (short)f2bf(hi.z); r[7] = (short)f2bf(hi.w);
    return r;
}

// ---------------- CSR phase A: block-staged distribute ----------------
// staging word: dst << 16 | src (both < 65536). bucket = word >> 23 (= dst>>7).

__global__ __launch_bounds__(256) void distribute_kernel(const int* __restrict__ dst,
                                                         const int* __restrict__ srcv,
                                                         int* __restrict__ gcnt,
                                                         unsigned int* __restrict__ staging,
                                                         int E, int NBc) {
    __shared__ unsigned int stage[EPB];      // bucket-sorted edges (32KB)
    __shared__ int hist[400];                // histogram, then LDS cursor
    __shared__ int lstart[400];              // exclusive prefix (incl. sentinel bucket)
    __shared__ int gbase[400];               // reserved global base per bucket
    __shared__ int scanbuf[256];
    int t = threadIdx.x;
    int e0 = blockIdx.x * EPB;
    unsigned int w[EPT];

    for (int b = t; b < NBc + 1; b += 256) hist[b] = 0;
    __syncthreads();

#pragma unroll
    for (int i = 0; i < EPT; ++i) {
        int e = e0 + i * 256 + t;            // coalesced
        unsigned int word = 0xFFFFFFFFu;     // sentinel -> bucket NBc
        if (e < E) word = ((unsigned int)dst[e] << 16) | (unsigned int)srcv[e];
        w[i] = word;
        int b = (int)(word >> 23); if (b > NBc) b = NBc;
        atomicAdd(&hist[b], 1);
    }
    __syncthreads();

    // exclusive scan over NBc+1 entries (2 per thread, Hillis-Steele on pairs)
    int b0 = 2 * t, b1 = 2 * t + 1;
    int h0 = (b0 <= NBc) ? hist[b0] : 0;
    int h1 = (b1 <= NBc) ? hist[b1] : 0;
    int pair = h0 + h1;
    scanbuf[t] = pair;
    __syncthreads();
    for (int off = 1; off < 256; off <<= 1) {
        int v = (t >= off) ? scanbuf[t - off] : 0;
        __syncthreads();
        scanbuf[t] += v;
        __syncthreads();
    }
    int excl = scanbuf[t] - pair;
    if (b0 <= NBc) lstart[b0] = excl;
    if (b1 <= NBc) lstart[b1] = excl + h0;
    __syncthreads();

    // one padded-line global atomic per non-empty bucket
    for (int b = t; b < NBc; b += 256) {
        int h = hist[b];
        gbase[b] = h ? atomicAdd(&gcnt[b * CPAD], h) : 0;
    }
    for (int b = t; b < NBc + 1; b += 256) hist[b] = lstart[b];   // -> LDS cursors
    __syncthreads();

#pragma unroll
    for (int i = 0; i < EPT; ++i) {
        unsigned int word = w[i];
        int b = (int)(word >> 23); if (b > NBc) b = NBc;
        int p = atomicAdd(&hist[b], 1);
        stage[p] = word;
    }
    __syncthreads();

    int total = lstart[NBc];                 // valid edges in this block
    for (int i = t; i < total; i += 256) {   // contiguous runs per bucket
        unsigned int word = stage[i];
        int b = (int)(word >> 23);
        int gpos = gbase[b] + (i - lstart[b]);
        staging[(size_t)b * BCAP + gpos] = word;
    }
}

// ---------------- CSR phase B: per-bucket local build (scan folded in) ----------------

__global__ __launch_bounds__(256) void build_kernel(const unsigned int* __restrict__ staging,
                                                    const int* __restrict__ gcnt,
                                                    int* __restrict__ row_ptr,
                                                    int* __restrict__ adj, int N, int NBc) {
    __shared__ int hist[NPB];   // histogram, then cursors
    __shared__ int scn[NPB];
    __shared__ int wsum[4];
    int b = blockIdx.x;
    int t = threadIdx.x;
    int n0 = b * NPB;
    int nb = N - n0; if (nb > NPB) nb = NPB;
    int ec = gcnt[b * CPAD];
    const unsigned int* st = staging + (size_t)b * BCAP;

    // exclusive bucket base: sum of gcnt[0..b)
    int a = 0;
    for (int j = t; j < b; j += 256) a += gcnt[j * CPAD];
#pragma unroll
    for (int off = 32; off; off >>= 1) a += __shfl_xor(a, off);
    if ((t & 63) == 0) wsum[t >> 6] = a;
    if (t < NPB) hist[t] = 0;
    __syncthreads();
    int bb = wsum[0] + wsum[1] + wsum[2] + wsum[3];

    for (int i = t; i < ec; i += 256)
        atomicAdd(&hist[(st[i] >> 16) & (NPB - 1)], 1);
    __syncthreads();

    int v = (t < NPB) ? hist[t] : 0;
    if (t < NPB) scn[t] = v;
    __syncthreads();
    for (int off = 1; off < NPB; off <<= 1) {
        int u = (t >= off && t < NPB) ? scn[t - off] : 0;
        __syncthreads();
        if (t < NPB) scn[t] += u;
        __syncthreads();
    }
    if (t < NPB) hist[t] = scn[t] - v;      // exclusive prefix -> cursor base
    if (t < nb) row_ptr[n0 + t] = bb + (scn[t] - v);
    if (b == NBc - 1 && t == 0) row_ptr[N] = bb + ec;   // total == E
    __syncthreads();

    for (int i = t; i < ec; i += 256) {
        unsigned int pk = st[i];
        int p = atomicAdd(&hist[(pk >> 16) & (NPB - 1)], 1);
        adj[bb + p] = (int)(pk & 0xffffu);
    }
}

// ---------------- weight casts: 6 tensors -> bf16 (x cast fused into GEMM0) ----------------

__global__ void cast_w_kernel(const float* p0, const float* p1, const float* p2,
                              const float* p3, const float* p4, const float* p5,
                              unsigned short* __restrict__ wbf) {
    int w = blockIdx.x * 256 + threadIdx.x;
    if (w < 40960) {
        const float* src;
        int local;
        if      (w < 8192)  { src = p0; local = w; }
        else if (w < 16384) { src = p1; local = w - 8192; }
        else if (w < 24576) { src = p2; local = w - 16384; }
        else if (w < 32768) { src = p3; local = w - 24576; }
        else if (w < 36864) { src = p4; local = w - 32768; }
        else                { src = p5; local = w - 36864; }
        float2 v = ((const float2*)src)[local];
        unsigned int p = (unsigned int)f2bf(v.x) | ((unsigned int)f2bf(v.y) << 16);
        ((unsigned int*)wbf)[w] = p;
    }
}

// ---------------- MFMA GEMM: all output columns in one block ----------------
// NJ = number of 16-col fragments (16 -> 256 cols = Wl|Wr 128+128; 8 -> 128).
// Each wave owns one 16-row fragment; A loaded once, reused NJ times.
// AF32: A is f32 (layer 0, x), cast to bf16 in-register (RNE, matches cast_w).

template<int NJ, int AF32>
__global__ __launch_bounds__(256) void gemm_mfma_kernel(const void* __restrict__ Hp,
                                                        const unsigned short* __restrict__ Wl,
                                                        const unsigned short* __restrict__ Wr,
                                                        unsigned short* __restrict__ C,
                                                        int N) {
    int wave = threadIdx.x >> 6;
    int lane = threadIdx.x & 63;
    int l15 = lane & 15, quad = lane >> 4;
    int m0 = blockIdx.x * 64 + wave * 16;
    int r0 = m0 + l15; if (r0 > N - 1) r0 = N - 1;

    f32x4 acc[NJ] = {};
#pragma unroll
    for (int ks = 0; ks < 4; ++ks) {
        int vidx = ks * 4 + quad;
        bf16x8 a;
        if constexpr (AF32) {
            const float4* A = (const float4*)((const float*)Hp + (size_t)r0 * 128);
            a = pack8(A[vidx * 2], A[vidx * 2 + 1]);
        } else {
            a = ((const bf16x8*)((const unsigned short*)Hp + (size_t)r0 * 128))[vidx];
        }
#pragma unroll
        for (int j = 0; j < NJ; ++j) {
            const unsigned short* W = (j < NJ / 2) ? Wl : Wr;
            int wr = ((j < NJ / 2) ? j : j - NJ / 2) * 16 + l15;
            bf16x8 b = ((const bf16x8*)(W + (size_t)wr * 128))[vidx];
            acc[j] = __builtin_amdgcn_mfma_f32_16x16x32_bf16(a, b, acc[j], 0, 0, 0);
        }
    }

    const int ldC = NJ * 16;
#pragma unroll
    for (int j = 0; j < NJ; ++j)
#pragma unroll
        for (int r = 0; r < 4; ++r) {
            int row = m0 + quad * 4 + r;
            if (row < N)
                C[(size_t)row * ldC + j * 16 + l15] = f2bf(acc[j][r]);
        }
}

// ---------------- Aggregation (layers 0,1): wave/node, vectorized 16B gathers ----
// lane = (g, c): g = lane>>4 edge slot (4 edges/round), c = lane&15 chunk
// (cols c*8..c*8+7). One dwordx4 load instruction = 4 rows x 256B = 1KB.

__global__ __launch_bounds__(256) void agg_relu_kernel(const unsigned short* __restrict__ C,
                                                       const int* __restrict__ row_ptr,
                                                       const int* __restrict__ adj,
                                                       const float* __restrict__ bias,
                                                       unsigned short* __restrict__ hout, int N) {
    int node = (int)((blockIdx.x * blockDim.x + threadIdx.x) >> 6);
    int lane = threadIdx.x & 63;
    if (node >= N) return;
    int g = lane >> 4;
    int c = lane & 15;
    int beg = row_ptr[node], end = row_ptr[node + 1];
    float p[8] = {};

    int e = beg;
    while (e < end) {
        int cnt = end - e; if (cnt > 64) cnt = 64;
        int ll = lane; if (ll > cnt - 1) ll = cnt - 1;
        int myidx = adj[e + ll];
        int c1 = cnt - 1;
        for (int i = 0; i < cnt; i += 16) {
            int t0 = i + g, t1 = i + 4 + g, t2 = i + 8 + g, t3 = i + 12 + g;
            int s0 = __shfl(myidx, t0 > c1 ? c1 : t0);
            int s1 = __shfl(myidx, t1 > c1 ? c1 : t1);
            int s2 = __shfl(myidx, t2 > c1 ? c1 : t2);
            int s3 = __shfl(myidx, t3 > c1 ? c1 : t3);
            float m0 = t0 < cnt ? 1.f : 0.f;
            float m1 = t1 < cnt ? 1.f : 0.f;
            float m2 = t2 < cnt ? 1.f : 0.f;
            float m3 = t3 < cnt ? 1.f : 0.f;
            bf16x8 v0 = ((const bf16x8*)(C + (size_t)s0 * 256))[c];
            bf16x8 v1 = ((const bf16x8*)(C + (size_t)s1 * 256))[c];
            bf16x8 v2 = ((const bf16x8*)(C + (size_t)s2 * 256))[c];
            bf16x8 v3 = ((const bf16x8*)(C + (size_t)s3 * 256))[c];
#pragma unroll
            for (int k = 0; k < 8; ++k) {
                p[k] += m0 * bf2f((unsigned short)v0[k]);
                p[k] += m1 * bf2f((unsigned short)v1[k]);
                p[k] += m2 * bf2f((unsigned short)v2[k]);
                p[k] += m3 * bf2f((unsigned short)v3[k]);
            }
        }
        e += cnt;
    }

    // reduce across the 4 edge-slot groups (lane bits 4,5)
#pragma unroll
    for (int k = 0; k < 8; ++k) {
        p[k] += __shfl_xor(p[k], 16);
        p[k] += __shfl_xor(p[k], 32);
    }

    int deg = end - beg;
    float inv = 1.0f / (float)(deg > 1 ? deg : 1);
    bf16x8 sv = ((const bf16x8*)(C + (size_t)node * 256))[16 + c];   // Wr self part
    float4 b0 = ((const float4*)bias)[2 * c];
    float4 b1 = ((const float4*)bias)[2 * c + 1];
    float bb[8] = {b0.x, b0.y, b0.z, b0.w, b1.x, b1.y, b1.z, b1.w};
    bf16x8 o;
#pragma unroll
    for (int k = 0; k < 8; ++k) {
        float v = fmaxf(p[k] * inv + bb[k] + bf2f((unsigned short)sv[k]), 0.f);
        o[k] = (short)f2bf(v);
    }
    if (g == 0)
        ((bf16x8*)(hout + (size_t)node * 128))[c] = o;
}

// ---------------- Final layer: vectorized gathers + fused log_softmax ----------------
// lane = (g, c): g = lane>>3 edge slot (8 edges/round), c = lane&7 chunk
// (cols c*8..c*8+7). Row = 64 cols bf16 = 128B = 8 chunks.

__global__ __launch_bounds__(256) void final_kernel(const unsigned short* __restrict__ C,
                                                    const int* __restrict__ row_ptr,
                                                    const int* __restrict__ adj,
                                                    const float* __restrict__ bias,
                                                    float* __restrict__ out, int N) {
    int node = (int)((blockIdx.x * blockDim.x + threadIdx.x) >> 6);
    int lane = threadIdx.x & 63;
    if (node >= N) return;
    int g = lane >> 3;
    int c = lane & 7;
    int beg = row_ptr[node], end = row_ptr[node + 1];
    float p[8] = {};

    int e = beg;
    while (e < end) {
        int cnt = end - e; if (cnt > 64) cnt = 64;
        int ll = lane; if (ll > cnt - 1) ll = cnt - 1;
        int myidx = adj[e + ll];
        int c1 = cnt - 1;
        for (int i = 0; i < cnt; i += 16) {
            int ta = i + g, tb = i + 8 + g;
            int sa = __shfl(myidx, ta > c1 ? c1 : ta);
            int sb = __shfl(myidx, tb > c1 ? c1 : tb);
            float ma = ta < cnt ? 1.f : 0.f;
            float mb = tb < cnt ? 1.f : 0.f;
            bf16x8 va = ((const bf16x8*)(C + (size_t)sa * 128))[c];
            bf16x8 vb = ((const bf16x8*)(C + (size_t)sb * 128))[c];
#pragma unroll
            for (int k = 0; k < 8; ++k) {
                p[k] += ma * bf2f((unsigned short)va[k]);
                p[k] += mb * bf2f((unsigned short)vb[k]);
            }
        }
        e += cnt;
    }

    // reduce across the 8 edge-slot groups (lane bits 3,4,5)
#pragma unroll
    for (int k = 0; k < 8; ++k) {
        p[k] += __shfl_xor(p[k], 8);
        p[k] += __shfl_xor(p[k], 16);
        p[k] += __shfl_xor(p[k], 32);
    }

    int deg = end - beg;
    float inv = 1.0f / (float)(deg > 1 ? deg : 1);
    bf16x8 sv = ((const bf16x8*)(C + (size_t)node * 128))[8 + c];    // Wr self part
    float4 b0 = ((const float4*)bias)[2 * c];
    float4 b1 = ((const float4*)bias)[2 * c + 1];
    float bb[8] = {b0.x, b0.y, b0.z, b0.w, b1.x, b1.y, b1.z, b1.w};
    float u[8];
#pragma unroll
    for (int k = 0; k < 8; ++k)
        u[k] = p[k] * inv + bb[k] + bf2f((unsigned short)sv[k]);

    // log_softmax over the 64 cols: per-lane max/sum over 8, then across c
    float m = u[0];
#pragma unroll
    for (int k = 1; k < 8; ++k) m = fmaxf(m, u[k]);
#pragma unroll
    for (int off = 1; off < 8; off <<= 1) m = fmaxf(m, __shfl_xor(m, off));
    float se = 0.f;
#pragma unroll
    for (int k = 0; k < 8; ++k) se += __expf(u[k] - m);
#pragma unroll
    for (int off = 1; off < 8; off <<= 1) se += __shfl_xor(se, off);
    float ls = __logf(se);

    if (g == 0) {
        float4 o0 = {u[0] - m - ls, u[1] - m - ls, u[2] - m - ls, u[3] - m - ls};
        float4 o1 = {u[4] - m - ls, u[5] - m - ls, u[6] - m - ls, u[7] - m - ls};
        ((float4*)(out + (size_t)node * 64))[2 * c] = o0;
        ((float4*)(out + (size_t)node * 64))[2 * c + 1] = o1;
    }
}

// ---------------- Launch ----------------

extern "C" void kernel_launch(void* const* d_in, const int* in_sizes, int n_in,
                              void* d_out, int out_size, void* d_ws, size_t ws_size,
                              hipStream_t stream) {
    const float* x   = (const float*)d_in[0];
    const int*   ei  = (const int*)d_in[1];
    const float* Wl0 = (const float*)d_in[2];
    const float* bl0 = (const float*)d_in[3];
    const float* Wr0 = (const float*)d_in[4];
    const float* Wl1 = (const float*)d_in[5];
    const float* bl1 = (const float*)d_in[6];
    const float* Wr1 = (const float*)d_in[7];
    const float* Wl2 = (const float*)d_in[8];
    const float* bl2 = (const float*)d_in[9];
    const float* Wr2 = (const float*)d_in[10];
    float* out = (float*)d_out;

    const int N  = in_sizes[0] / 128;   // 50000
    const int E  = in_sizes[1] / 2;     // 800000
    const int NB = (N + NPB - 1) / NPB; // 391 buckets

    char* ws = (char*)d_ws;
    auto alloc = [&](size_t bytes) {
        char* p = ws;
        ws += (bytes + 255) & ~(size_t)255;
        return p;
    };
    int*   row_ptr    = (int*)alloc((size_t)(N + 1) * 4);
    int*   adj        = (int*)alloc((size_t)E * 4);
    int*   gcnt       = (int*)alloc((size_t)NB * CPAD * 4);  // 64B-padded counters
    unsigned int* staging = (unsigned int*)alloc((size_t)NB * BCAP * 4);
    unsigned short* wbf = (unsigned short*)alloc((size_t)81920 * 2);
    unsigned short* C   = (unsigned short*)alloc((size_t)N * 256 * 2);
    unsigned short* hA  = (unsigned short*)alloc((size_t)N * 128 * 2);
    unsigned short* hB  = (unsigned short*)alloc((size_t)N * 128 * 2);

    const int* dstp = ei;       // edge_index row 0 = dst
    const int* srcp = ei + E;   // edge_index row 1 = src

    // CSR build (block-staged distribute -> per-bucket build w/ inline base scan)
    hipMemsetAsync(gcnt, 0, (size_t)NB * CPAD * 4, stream);
    int distBlocks = (E + EPB - 1) / EPB;   // 98
    distribute_kernel<<<distBlocks, 256, 0, stream>>>(dstp, srcp, gcnt, staging, E, NB);
    build_kernel<<<NB, 256, 0, stream>>>(staging, gcnt, row_ptr, adj, N, NB);

    // weight casts (x cast is fused into GEMM0)
    cast_w_kernel<<<160, 256, 0, stream>>>(Wl0, Wr0, Wl1, Wr1, Wl2, Wr2, wbf);
    unsigned short* wl0 = wbf;
    unsigned short* wr0 = wbf + 16384;
    unsigned short* wl1 = wbf + 32768;
    unsigned short* wr1 = wbf + 49152;
    unsigned short* wl2 = wbf + 65536;
    unsigned short* wr2 = wbf + 73728;

    dim3 blk(256);
    int gemmRows = (N + 63) / 64;       // 782 blocks, 4 waves x 16 rows each
    int aggBlocks = (N * 64 + 255) / 256;

    // Layer 0 (A = f32 x, cast in-kernel; x read exactly once)
    gemm_mfma_kernel<16, 1><<<gemmRows, blk, 0, stream>>>((const void*)x, wl0, wr0, C, N);
    agg_relu_kernel<<<aggBlocks, blk, 0, stream>>>(C, row_ptr, adj, bl0, hA, N);
    // Layer 1
    gemm_mfma_kernel<16, 0><<<gemmRows, blk, 0, stream>>>((const void*)hA, wl1, wr1, C, N);
    agg_relu_kernel<<<aggBlocks, blk, 0, stream>>>(C, row_ptr, adj, bl1, hB, N);
    // Layer 2 + log_softmax
    gemm_mfma_kernel<8, 0><<<gemmRows, blk, 0, stream>>>((const void*)hB, wl2, wr2, C, N);
    final_kernel<<<aggBlocks, blk, 0, stream>>>(C, row_ptr, adj, bl2, out, N);
}

// Round 3
// 273.345 us; speedup vs baseline: 1.1399x; 1.1399x over previous
//
#include <hip/hip_runtime.h>
#include <hip/hip_bf16.h>

// GraphSAGE 3-layer forward, MI355X. Round 8:
//  - GEMM: B (weights) preloaded to registers ONCE per wave as independent
//    loads (16x bf16x8 = 64 VGPR), then M/K loops are A-load + MFMA only.
//    R7 was latency-bound (47us/GEMM, MfmaUtil 2.4%, occ 20%): at 76 VGPR
//    the compiler serialized load-B -> MFMA per K-step (64 dependent L2
//    hops/wave). Block = 64 rows x 256 cols; wave owns 64-col group (CF=4);
//    A read once per block (waves share via L1), C written once.
//  - x f32->bf16 cast stays fused into GEMM0; NJ->CF template (CF=2 layer 2).
//  - vectorized agg/final gathers (R6) kept; distribute/build (R5/R6) kept.

typedef __attribute__((ext_vector_type(8))) short bf16x8;
typedef __attribute__((ext_vector_type(4))) float f32x4;

#define NPB 128            // nodes per bucket (bucket = dst >> 7)
#define BCAP 2560          // per-bucket staging capacity (mean 2048, sd ~45)
#define EPB 8192           // edges per distribute block
#define EPT 32             // edges per thread (256 thr)
#define CPAD 16            // global counter stride in ints (64B line each)

__device__ __forceinline__ unsigned short f2bf(float f) {
    unsigned int u = __builtin_bit_cast(unsigned int, f);
    u += 0x7fffu + ((u >> 16) & 1u);           // round-to-nearest-even
    return (unsigned short)(u >> 16);
}
__device__ __forceinline__ float bf2f(unsigned int bits16) {
    return __builtin_bit_cast(float, bits16 << 16);
}
__device__ __forceinline__ bf16x8 pack8(float4 lo, float4 hi) {
    bf16x8 r;
    r[0] = (short)f2bf(lo.x); r[1] = (short)f2bf(lo.y);
    r[2] = (short)f2bf(lo.z); r[3] = (short)f2bf(lo.w);
    r[4] = (short)f2bf(hi.x); r[5] = (short)f2bf(hi.y);
    r[6] = (short)f2bf(hi.z); r[7] = (short)f2bf(hi.w);
    return r;
}

// ---------------- CSR phase A: block-staged distribute ----------------
// staging word: dst << 16 | src (both < 65536). bucket = word >> 23 (= dst>>7).

__global__ __launch_bounds__(256) void distribute_kernel(const int* __restrict__ dst,
                                                         const int* __restrict__ srcv,
                                                         int* __restrict__ gcnt,
                                                         unsigned int* __restrict__ staging,
                                                         int E, int NBc) {
    __shared__ unsigned int stage[EPB];      // bucket-sorted edges (32KB)
    __shared__ int hist[400];                // histogram, then LDS cursor
    __shared__ int lstart[400];              // exclusive prefix (incl. sentinel bucket)
    __shared__ int gbase[400];               // reserved global base per bucket
    __shared__ int scanbuf[256];
    int t = threadIdx.x;
    int e0 = blockIdx.x * EPB;
    unsigned int w[EPT];

    for (int b = t; b < NBc + 1; b += 256) hist[b] = 0;
    __syncthreads();

#pragma unroll
    for (int i = 0; i < EPT; ++i) {
        int e = e0 + i * 256 + t;            // coalesced
        unsigned int word = 0xFFFFFFFFu;     // sentinel -> bucket NBc
        if (e < E) word = ((unsigned int)dst[e] << 16) | (unsigned int)srcv[e];
        w[i] = word;
        int b = (int)(word >> 23); if (b > NBc) b = NBc;
        atomicAdd(&hist[b], 1);
    }
    __syncthreads();

    // exclusive scan over NBc+1 entries (2 per thread, Hillis-Steele on pairs)
    int b0 = 2 * t, b1 = 2 * t + 1;
    int h0 = (b0 <= NBc) ? hist[b0] : 0;
    int h1 = (b1 <= NBc) ? hist[b1] : 0;
    int pair = h0 + h1;
    scanbuf[t] = pair;
    __syncthreads();
    for (int off = 1; off < 256; off <<= 1) {
        int v = (t >= off) ? scanbuf[t - off] : 0;
        __syncthreads();
        scanbuf[t] += v;
        __syncthreads();
    }
    int excl = scanbuf[t] - pair;
    if (b0 <= NBc) lstart[b0] = excl;
    if (b1 <= NBc) lstart[b1] = excl + h0;
    __syncthreads();

    // one padded-line global atomic per non-empty bucket
    for (int b = t; b < NBc; b += 256) {
        int h = hist[b];
        gbase[b] = h ? atomicAdd(&gcnt[b * CPAD], h) : 0;
    }
    for (int b = t; b < NBc + 1; b += 256) hist[b] = lstart[b];   // -> LDS cursors
    __syncthreads();

#pragma unroll
    for (int i = 0; i < EPT; ++i) {
        unsigned int word = w[i];
        int b = (int)(word >> 23); if (b > NBc) b = NBc;
        int p = atomicAdd(&hist[b], 1);
        stage[p] = word;
    }
    __syncthreads();

    int total = lstart[NBc];                 // valid edges in this block
    for (int i = t; i < total; i += 256) {   // contiguous runs per bucket
        unsigned int word = stage[i];
        int b = (int)(word >> 23);
        int gpos = gbase[b] + (i - lstart[b]);
        staging[(size_t)b * BCAP + gpos] = word;
    }
}

// ---------------- CSR phase B: per-bucket local build (scan folded in) ----------------

__global__ __launch_bounds__(256) void build_kernel(const unsigned int* __restrict__ staging,
                                                    const int* __restrict__ gcnt,
                                                    int* __restrict__ row_ptr,
                                                    int* __restrict__ adj, int N, int NBc) {
    __shared__ int hist[NPB];   // histogram, then cursors
    __shared__ int scn[NPB];
    __shared__ int wsum[4];
    int b = blockIdx.x;
    int t = threadIdx.x;
    int n0 = b * NPB;
    int nb = N - n0; if (nb > NPB) nb = NPB;
    int ec = gcnt[b * CPAD];
    const unsigned int* st = staging + (size_t)b * BCAP;

    // exclusive bucket base: sum of gcnt[0..b)
    int a = 0;
    for (int j = t; j < b; j += 256) a += gcnt[j * CPAD];
#pragma unroll
    for (int off = 32; off; off >>= 1) a += __shfl_xor(a, off);
    if ((t & 63) == 0) wsum[t >> 6] = a;
    if (t < NPB) hist[t] = 0;
    __syncthreads();
    int bb = wsum[0] + wsum[1] + wsum[2] + wsum[3];

    for (int i = t; i < ec; i += 256)
        atomicAdd(&hist[(st[i] >> 16) & (NPB - 1)], 1);
    __syncthreads();

    int v = (t < NPB) ? hist[t] : 0;
    if (t < NPB) scn[t] = v;
    __syncthreads();
    for (int off = 1; off < NPB; off <<= 1) {
        int u = (t >= off && t < NPB) ? scn[t - off] : 0;
        __syncthreads();
        if (t < NPB) scn[t] += u;
        __syncthreads();
    }
    if (t < NPB) hist[t] = scn[t] - v;      // exclusive prefix -> cursor base
    if (t < nb) row_ptr[n0 + t] = bb + (scn[t] - v);
    if (b == NBc - 1 && t == 0) row_ptr[N] = bb + ec;   // total == E
    __syncthreads();

    for (int i = t; i < ec; i += 256) {
        unsigned int pk = st[i];
        int p = atomicAdd(&hist[(pk >> 16) & (NPB - 1)], 1);
        adj[bb + p] = (int)(pk & 0xffffu);
    }
}

// ---------------- weight casts: 6 tensors -> bf16 (x cast fused into GEMM0) ----------------

__global__ void cast_w_kernel(const float* p0, const float* p1, const float* p2,
                              const float* p3, const float* p4, const float* p5,
                              unsigned short* __restrict__ wbf) {
    int w = blockIdx.x * 256 + threadIdx.x;
    if (w < 40960) {
        const float* src;
        int local;
        if      (w < 8192)  { src = p0; local = w; }
        else if (w < 16384) { src = p1; local = w - 8192; }
        else if (w < 24576) { src = p2; local = w - 16384; }
        else if (w < 32768) { src = p3; local = w - 24576; }
        else if (w < 36864) { src = p4; local = w - 32768; }
        else                { src = p5; local = w - 36864; }
        float2 v = ((const float2*)src)[local];
        unsigned int p = (unsigned int)f2bf(v.x) | ((unsigned int)f2bf(v.y) << 16);
        ((unsigned int*)wbf)[w] = p;
    }
}

// ---------------- MFMA GEMM: B in registers, one pass over A ----------------
// Block = 64 rows x (4*CF*16) cols; wave w owns col-group w (CF 16-col frags).
// Each wave preloads its CF*4 B fragments once (independent loads, one drain),
// then loops 4 row-fragments: load A, 4*CF MFMAs. A read once per block.
// AF32: A is f32 (layer 0, x), cast to bf16 in-register (RNE, matches cast_w).

template<int CF, int AF32>
__global__ __launch_bounds__(256) void gemm_mfma_kernel(const void* __restrict__ Hp,
                                                        const unsigned short* __restrict__ Wl,
                                                        const unsigned short* __restrict__ Wr,
                                                        unsigned short* __restrict__ C,
                                                        int N) {
    int wave = threadIdx.x >> 6;
    int lane = threadIdx.x & 63;
    int l15 = lane & 15, quad = lane >> 4;
    const int NCOL = 4 * CF * 16;          // 256 (layers 0/1) or 128 (layer 2)
    const int half = NCOL >> 1;

    // preload B fragments (loop-invariant, independent)
    bf16x8 bfr[CF][4];
#pragma unroll
    for (int cf = 0; cf < CF; ++cf) {
        int col0 = (wave * CF + cf) * 16;
        const unsigned short* W = (col0 < half) ? Wl : Wr;
        int wr = (col0 < half ? col0 : col0 - half) + l15;
#pragma unroll
        for (int ks = 0; ks < 4; ++ks)
            bfr[cf][ks] = ((const bf16x8*)(W + (size_t)wr * 128))[ks * 4 + quad];
    }

    int m0 = blockIdx.x * 64;
    f32x4 acc[4][CF] = {};
#pragma unroll
    for (int rf = 0; rf < 4; ++rf) {
        int r0 = m0 + rf * 16 + l15; if (r0 > N - 1) r0 = N - 1;
#pragma unroll
        for (int ks = 0; ks < 4; ++ks) {
            int vidx = ks * 4 + quad;
            bf16x8 a;
            if constexpr (AF32) {
                const float4* A = (const float4*)((const float*)Hp + (size_t)r0 * 128);
                a = pack8(A[vidx * 2], A[vidx * 2 + 1]);
            } else {
                a = ((const bf16x8*)((const unsigned short*)Hp + (size_t)r0 * 128))[vidx];
            }
#pragma unroll
            for (int cf = 0; cf < CF; ++cf)
                acc[rf][cf] = __builtin_amdgcn_mfma_f32_16x16x32_bf16(a, bfr[cf][ks],
                                                                      acc[rf][cf], 0, 0, 0);
        }
    }

#pragma unroll
    for (int rf = 0; rf < 4; ++rf)
#pragma unroll
        for (int cf = 0; cf < CF; ++cf)
#pragma unroll
            for (int r = 0; r < 4; ++r) {
                int row = m0 + rf * 16 + quad * 4 + r;
                if (row < N)
                    C[(size_t)row * NCOL + (wave * CF + cf) * 16 + l15] = f2bf(acc[rf][cf][r]);
            }
}

// ---------------- Aggregation (layers 0,1): wave/node, vectorized 16B gathers ----
// lane = (g, c): g = lane>>4 edge slot (4 edges/round), c = lane&15 chunk
// (cols c*8..c*8+7). One dwordx4 load instruction = 4 rows x 256B = 1KB.

__global__ __launch_bounds__(256) void agg_relu_kernel(const unsigned short* __restrict__ C,
                                                       const int* __restrict__ row_ptr,
                                                       const int* __restrict__ adj,
                                                       const float* __restrict__ bias,
                                                       unsigned short* __restrict__ hout, int N) {
    int node = (int)((blockIdx.x * blockDim.x + threadIdx.x) >> 6);
    int lane = threadIdx.x & 63;
    if (node >= N) return;
    int g = lane >> 4;
    int c = lane & 15;
    int beg = row_ptr[node], end = row_ptr[node + 1];
    float p[8] = {};

    int e = beg;
    while (e < end) {
        int cnt = end - e; if (cnt > 64) cnt = 64;
        int ll = lane; if (ll > cnt - 1) ll = cnt - 1;
        int myidx = adj[e + ll];
        int c1 = cnt - 1;
        for (int i = 0; i < cnt; i += 16) {
            int t0 = i + g, t1 = i + 4 + g, t2 = i + 8 + g, t3 = i + 12 + g;
            int s0 = __shfl(myidx, t0 > c1 ? c1 : t0);
            int s1 = __shfl(myidx, t1 > c1 ? c1 : t1);
            int s2 = __shfl(myidx, t2 > c1 ? c1 : t2);
            int s3 = __shfl(myidx, t3 > c1 ? c1 : t3);
            float m0 = t0 < cnt ? 1.f : 0.f;
            float m1 = t1 < cnt ? 1.f : 0.f;
            float m2 = t2 < cnt ? 1.f : 0.f;
            float m3 = t3 < cnt ? 1.f : 0.f;
            bf16x8 v0 = ((const bf16x8*)(C + (size_t)s0 * 256))[c];
            bf16x8 v1 = ((const bf16x8*)(C + (size_t)s1 * 256))[c];
            bf16x8 v2 = ((const bf16x8*)(C + (size_t)s2 * 256))[c];
            bf16x8 v3 = ((const bf16x8*)(C + (size_t)s3 * 256))[c];
#pragma unroll
            for (int k = 0; k < 8; ++k) {
                p[k] += m0 * bf2f((unsigned short)v0[k]);
                p[k] += m1 * bf2f((unsigned short)v1[k]);
                p[k] += m2 * bf2f((unsigned short)v2[k]);
                p[k] += m3 * bf2f((unsigned short)v3[k]);
            }
        }
        e += cnt;
    }

    // reduce across the 4 edge-slot groups (lane bits 4,5)
#pragma unroll
    for (int k = 0; k < 8; ++k) {
        p[k] += __shfl_xor(p[k], 16);
        p[k] += __shfl_xor(p[k], 32);
    }

    int deg = end - beg;
    float inv = 1.0f / (float)(deg > 1 ? deg : 1);
    bf16x8 sv = ((const bf16x8*)(C + (size_t)node * 256))[16 + c];   // Wr self part
    float4 b0 = ((const float4*)bias)[2 * c];
    float4 b1 = ((const float4*)bias)[2 * c + 1];
    float bb[8] = {b0.x, b0.y, b0.z, b0.w, b1.x, b1.y, b1.z, b1.w};
    bf16x8 o;
#pragma unroll
    for (int k = 0; k < 8; ++k) {
        float v = fmaxf(p[k] * inv + bb[k] + bf2f((unsigned short)sv[k]), 0.f);
        o[k] = (short)f2bf(v);
    }
    if (g == 0)
        ((bf16x8*)(hout + (size_t)node * 128))[c] = o;
}

// ---------------- Final layer: vectorized gathers + fused log_softmax ----------------
// lane = (g, c): g = lane>>3 edge slot (8 edges/round), c = lane&7 chunk
// (cols c*8..c*8+7). Row = 64 cols bf16 = 128B = 8 chunks.

__global__ __launch_bounds__(256) void final_kernel(const unsigned short* __restrict__ C,
                                                    const int* __restrict__ row_ptr,
                                                    const int* __restrict__ adj,
                                                    const float* __restrict__ bias,
                                                    float* __restrict__ out, int N) {
    int node = (int)((blockIdx.x * blockDim.x + threadIdx.x) >> 6);
    int lane = threadIdx.x & 63;
    if (node >= N) return;
    int g = lane >> 3;
    int c = lane & 7;
    int beg = row_ptr[node], end = row_ptr[node + 1];
    float p[8] = {};

    int e = beg;
    while (e < end) {
        int cnt = end - e; if (cnt > 64) cnt = 64;
        int ll = lane; if (ll > cnt - 1) ll = cnt - 1;
        int myidx = adj[e + ll];
        int c1 = cnt - 1;
        for (int i = 0; i < cnt; i += 16) {
            int ta = i + g, tb = i + 8 + g;
            int sa = __shfl(myidx, ta > c1 ? c1 : ta);
            int sb = __shfl(myidx, tb > c1 ? c1 : tb);
            float ma = ta < cnt ? 1.f : 0.f;
            float mb = tb < cnt ? 1.f : 0.f;
            bf16x8 va = ((const bf16x8*)(C + (size_t)sa * 128))[c];
            bf16x8 vb = ((const bf16x8*)(C + (size_t)sb * 128))[c];
#pragma unroll
            for (int k = 0; k < 8; ++k) {
                p[k] += ma * bf2f((unsigned short)va[k]);
                p[k] += mb * bf2f((unsigned short)vb[k]);
            }
        }
        e += cnt;
    }

    // reduce across the 8 edge-slot groups (lane bits 3,4,5)
#pragma unroll
    for (int k = 0; k < 8; ++k) {
        p[k] += __shfl_xor(p[k], 8);
        p[k] += __shfl_xor(p[k], 16);
        p[k] += __shfl_xor(p[k], 32);
    }

    int deg = end - beg;
    float inv = 1.0f / (float)(deg > 1 ? deg : 1);
    bf16x8 sv = ((const bf16x8*)(C + (size_t)node * 128))[8 + c];    // Wr self part
    float4 b0 = ((const float4*)bias)[2 * c];
    float4 b1 = ((const float4*)bias)[2 * c + 1];
    float bb[8] = {b0.x, b0.y, b0.z, b0.w, b1.x, b1.y, b1.z, b1.w};
    float u[8];
#pragma unroll
    for (int k = 0; k < 8; ++k)
        u[k] = p[k] * inv + bb[k] + bf2f((unsigned short)sv[k]);

    // log_softmax over the 64 cols: per-lane max/sum over 8, then across c
    float m = u[0];
#pragma unroll
    for (int k = 1; k < 8; ++k) m = fmaxf(m, u[k]);
#pragma unroll
    for (int off = 1; off < 8; off <<= 1) m = fmaxf(m, __shfl_xor(m, off));
    float se = 0.f;
#pragma unroll
    for (int k = 0; k < 8; ++k) se += __expf(u[k] - m);
#pragma unroll
    for (int off = 1; off < 8; off <<= 1) se += __shfl_xor(se, off);
    float ls = __logf(se);

    if (g == 0) {
        float4 o0 = {u[0] - m - ls, u[1] - m - ls, u[2] - m - ls, u[3] - m - ls};
        float4 o1 = {u[4] - m - ls, u[5] - m - ls, u[6] - m - ls, u[7] - m - ls};
        ((float4*)(out + (size_t)node * 64))[2 * c] = o0;
        ((float4*)(out + (size_t)node * 64))[2 * c + 1] = o1;
    }
}

// ---------------- Launch ----------------

extern "C" void kernel_launch(void* const* d_in, const int* in_sizes, int n_in,
                              void* d_out, int out_size, void* d_ws, size_t ws_size,
                              hipStream_t stream) {
    const float* x   = (const float*)d_in[0];
    const int*   ei  = (const int*)d_in[1];
    const float* Wl0 = (const float*)d_in[2];
    const float* bl0 = (const float*)d_in[3];
    const float* Wr0 = (const float*)d_in[4];
    const float* Wl1 = (const float*)d_in[5];
    const float* bl1 = (const float*)d_in[6];
    const float* Wr1 = (const float*)d_in[7];
    const float* Wl2 = (const float*)d_in[8];
    const float* bl2 = (const float*)d_in[9];
    const float* Wr2 = (const float*)d_in[10];
    float* out = (float*)d_out;

    const int N  = in_sizes[0] / 128;   // 50000
    const int E  = in_sizes[1] / 2;     // 800000
    const int NB = (N + NPB - 1) / NPB; // 391 buckets

    char* ws = (char*)d_ws;
    auto alloc = [&](size_t bytes) {
        char* p = ws;
        ws += (bytes + 255) & ~(size_t)255;
        return p;
    };
    int*   row_ptr    = (int*)alloc((size_t)(N + 1) * 4);
    int*   adj        = (int*)alloc((size_t)E * 4);
    int*   gcnt       = (int*)alloc((size_t)NB * CPAD * 4);  // 64B-padded counters
    unsigned int* staging = (unsigned int*)alloc((size_t)NB * BCAP * 4);
    unsigned short* wbf = (unsigned short*)alloc((size_t)81920 * 2);
    unsigned short* C   = (unsigned short*)alloc((size_t)N * 256 * 2);
    unsigned short* hA  = (unsigned short*)alloc((size_t)N * 128 * 2);
    unsigned short* hB  = (unsigned short*)alloc((size_t)N * 128 * 2);

    const int* dstp = ei;       // edge_index row 0 = dst
    const int* srcp = ei + E;   // edge_index row 1 = src

    // CSR build (block-staged distribute -> per-bucket build w/ inline base scan)
    hipMemsetAsync(gcnt, 0, (size_t)NB * CPAD * 4, stream);
    int distBlocks = (E + EPB - 1) / EPB;   // 98
    distribute_kernel<<<distBlocks, 256, 0, stream>>>(dstp, srcp, gcnt, staging, E, NB);
    build_kernel<<<NB, 256, 0, stream>>>(staging, gcnt, row_ptr, adj, N, NB);

    // weight casts (x cast is fused into GEMM0)
    cast_w_kernel<<<160, 256, 0, stream>>>(Wl0, Wr0, Wl1, Wr1, Wl2, Wr2, wbf);
    unsigned short* wl0 = wbf;
    unsigned short* wr0 = wbf + 16384;
    unsigned short* wl1 = wbf + 32768;
    unsigned short* wr1 = wbf + 49152;
    unsigned short* wl2 = wbf + 65536;
    unsigned short* wr2 = wbf + 73728;

    dim3 blk(256);
    int gemmRows = (N + 63) / 64;       // 782 blocks, 64 rows each
    int aggBlocks = (N * 64 + 255) / 256;

    // Layer 0 (A = f32 x, cast in-kernel; x read exactly once)
    gemm_mfma_kernel<4, 1><<<gemmRows, blk, 0, stream>>>((const void*)x, wl0, wr0, C, N);
    agg_relu_kernel<<<aggBlocks, blk, 0, stream>>>(C, row_ptr, adj, bl0, hA, N);
    // Layer 1
    gemm_mfma_kernel<4, 0><<<gemmRows, blk, 0, stream>>>((const void*)hA, wl1, wr1, C, N);
    agg_relu_kernel<<<aggBlocks, blk, 0, stream>>>(C, row_ptr, adj, bl1, hB, N);
    // Layer 2 + log_softmax
    gemm_mfma_kernel<2, 0><<<gemmRows, blk, 0, stream>>>((const void*)hB, wl2, wr2, C, N);
    final_kernel<<<aggBlocks, blk, 0, stream>>>(C, row_ptr, adj, bl2, out, N);
}